// Round 16
// baseline (255.464 us; speedup 1.0000x reference)
//
#include <hip/hip_runtime.h>

#define BLOCK 512   // 8 waves
#define GRID  768   // 3 blocks/CU x 256 CU; LDS 53760*3 = 161280 <= 163840

typedef __attribute__((ext_vector_type(8))) short short8;   // 8 x bf16
typedef __attribute__((ext_vector_type(4))) float f32x4;    // MFMA C/D frag

#define TWOLOG2E  2.8853900817779268f
#define NLOG2E   -1.4426950408889634f
#define HP 72   // 144B pitch: 16B-aligned (R12 lesson); b128 reads 2-way = free

__device__ __forceinline__ unsigned short f2bf(float f) {
    unsigned u = __builtin_bit_cast(unsigned, f);
    u += 0x7FFFu + ((u >> 16) & 1u);
    return (unsigned short)(u >> 16);
}

__device__ __forceinline__ unsigned pkbf(float lo, float hi) {
    unsigned r;
    asm("v_cvt_pk_bf16_f32 %0, %1, %2" : "=v"(r) : "v"(lo), "v"(hi));
    return r;
}

__device__ __forceinline__ float tanh_z(float z) {
    float e = __builtin_amdgcn_exp2f(z);
    return fmaf(-2.0f, __builtin_amdgcn_rcpf(1.0f + e), 1.0f);
}

// LN+tanh; bias already in acc via MFMA C-init, so stats-only prologue.
#define LN_T(PG, PT, A)                                                       \
    {                                                                         \
        float s_ = 0.f, q_ = 0.f;                                             \
        _Pragma("unroll")                                                     \
        for (int m = 0; m < 4; ++m) {                                         \
            s_ += (A[m][0] + A[m][1]) + (A[m][2] + A[m][3]);                  \
            q_ = fmaf(A[m][0], A[m][0], q_); q_ = fmaf(A[m][1], A[m][1], q_); \
            q_ = fmaf(A[m][2], A[m][2], q_); q_ = fmaf(A[m][3], A[m][3], q_); \
        }                                                                     \
        s_ += __shfl_xor(s_, 16); s_ += __shfl_xor(s_, 32);                   \
        q_ += __shfl_xor(q_, 16); q_ += __shfl_xor(q_, 32);                   \
        const float mu = s_ * 0.015625f;                                      \
        float var = fmaf(q_, 0.015625f, -mu * mu);                            \
        var = fmaxf(var, 0.0f);                                               \
        const float rs = __builtin_amdgcn_rsqf(var + 1e-5f);                  \
        const float mrs = mu * rs;                                            \
        _Pragma("unroll")                                                     \
        for (int m = 0; m < 4; ++m) {                                         \
            const float4 pg = *reinterpret_cast<const float4*>(               \
                plds + (PG) * 64 + m * 16 + kg4);                             \
            const float4 pt = *reinterpret_cast<const float4*>(               \
                plds + (PT) * 64 + m * 16 + kg4);                             \
            A[m][0] = tanh_z(fmaf(fmaf(A[m][0], rs, -mrs), pg.x, pt.x));      \
            A[m][1] = tanh_z(fmaf(fmaf(A[m][1], rs, -mrs), pg.y, pt.y));      \
            A[m][2] = tanh_z(fmaf(fmaf(A[m][2], rs, -mrs), pg.z, pt.z));      \
            A[m][3] = tanh_z(fmaf(fmaf(A[m][3], rs, -mrs), pg.w, pt.w));      \
        }                                                                     \
    }

#define H_STORE(A)                                                            \
    _Pragma("unroll")                                                         \
    for (int m = 0; m < 4; ++m) {                                             \
        uint2 u2;                                                             \
        u2.x = pkbf(A[m][0], A[m][1]);                                        \
        u2.y = pkbf(A[m][2], A[m][3]);                                        \
        *reinterpret_cast<uint2*>(hwv + cl * HP + m * 16 + kg4) = u2;         \
    }

// bias as MFMA C-init: acc starts at b (one ds_read_b128 per m)
#define ACC_INIT(ACC, PB)                                                     \
    _Pragma("unroll")                                                         \
    for (int m = 0; m < 4; ++m)                                               \
        ACC[m] = __builtin_bit_cast(f32x4, *reinterpret_cast<const float4*>(  \
            plds + (PB) * 64 + m * 16 + kg4));

#define L23_MFMA(ACC, BASE)                                                   \
    _Pragma("unroll")                                                         \
    for (int kb = 0; kb < 2; ++kb) {                                          \
        const short8 hf = *reinterpret_cast<const short8*>(                   \
            hwv + cl * HP + kb * 32 + kg * 8);                                \
        _Pragma("unroll")                                                     \
        for (int m = 0; m < 4; ++m) {                                         \
            const short8 wf = *reinterpret_cast<const short8*>(               \
                &wlds[((BASE) + m * 2 + kb) * 512 + lane * 8]);               \
            ACC[m] = __builtin_amdgcn_mfma_f32_16x16x32_bf16(wf, hf, ACC[m], 0, 0, 0); \
        }                                                                     \
    }

#define LDIDX(T, A_, B_)                                                      \
    {                                                                         \
        const int tc_ = min((T), ntiles - 1);                                 \
        const int er_ = min((tc_ << 4) + cl, E - 1);                          \
        A_ = ei[er_]; B_ = ei[E + er_];                                       \
    }

template<bool PREBF>
__global__ __launch_bounds__(BLOCK, 6) void edge_mlp_t(
    const void* __restrict__ xsrc, const int* __restrict__ ei,
    const float* __restrict__ W1, const float* __restrict__ b1,
    const float* __restrict__ g1, const float* __restrict__ bt1,
    const float* __restrict__ W2, const float* __restrict__ b2,
    const float* __restrict__ g2, const float* __restrict__ bt2,
    const float* __restrict__ W3, const float* __restrict__ b3,
    const float* __restrict__ g3, const float* __restrict__ bt3,
    const float* __restrict__ W4, const float* __restrict__ b4,
    float* __restrict__ out, int E)
{
    __shared__ unsigned short wlds[32 * 512];        // 32 KiB W^T frags
    __shared__ unsigned short hlds[8 * 16 * HP];     // 18 KiB: per-wave h tile
    __shared__ float plds[10 * 64];                  // 2.5 KiB params

    const int tid  = threadIdx.x;
    const int widx = tid >> 6;
    const int lane = tid & 63;
    const int kg   = lane >> 4;
    const int cl   = lane & 15;
    const int kg4  = kg * 4;

    for (int fi = widx; fi < 32; fi += 8) {
        const float* Wsrc; int m, kb;
        if (fi < 16) { Wsrc = W1; m = fi >> 2; kb = fi & 3; }
        else { int f = fi - 16; Wsrc = (f < 8) ? W2 : W3; f &= 7; m = f >> 1; kb = f & 1; }
        const float* src = Wsrc + (kb * 32 + kg * 8) * 64 + m * 16 + cl;
        short8 pk8;
        #pragma unroll
        for (int j = 0; j < 8; ++j) pk8[j] = (short)f2bf(src[j * 64]);
        *reinterpret_cast<short8*>(&wlds[fi * 512 + lane * 8]) = pk8;
    }
    for (int i = tid; i < 640; i += BLOCK) {
        const int p = i >> 6, c = i & 63;
        const float* sp; float sc;
        switch (p) {
            case 0: sp = b1;  sc = 1.0f;     break;
            case 1: sp = g1;  sc = TWOLOG2E; break;
            case 2: sp = bt1; sc = TWOLOG2E; break;
            case 3: sp = b2;  sc = 1.0f;     break;
            case 4: sp = g2;  sc = TWOLOG2E; break;
            case 5: sp = bt2; sc = TWOLOG2E; break;
            case 6: sp = b3;  sc = 1.0f;     break;
            case 7: sp = g3;  sc = TWOLOG2E; break;
            case 8: sp = bt3; sc = TWOLOG2E; break;
            default: sp = W4; sc = NLOG2E;   break;
        }
        plds[i] = sp[c] * sc;
    }
    const float b4s = b4[0] * NLOG2E;
    __syncthreads();

    const unsigned short* xb = (const unsigned short*)xsrc;
    const float*          xf = (const float*)xsrc;
    unsigned short* hwv = hlds + widx * (16 * HP);

    const int ntiles = (E + 15) >> 4;
    const int NW = (int)gridDim.x * 8;

    int t = (int)blockIdx.x * 8 + widx;
    int ns, ne;
    LDIDX(t, ns, ne);

    for (; t < ntiles; t += NW) {
        // index prefetch (only cross-tile state: 2 regs)
        int nns, nne;
        LDIDX(t + NW, nns, nne);

        // issue all 8 gather loads; 6 waves/SIMD TLP hides the latency
        float4 u[8];
        short8 xa[4];
        #pragma unroll
        for (int kb = 0; kb < 4; ++kb) {
            const unsigned off = (unsigned)(kb < 2 ? ns : ne) * 64u
                               + (unsigned)((kb & 1) * 32 + kg * 8);
            if constexpr (PREBF) {
                xa[kb] = *reinterpret_cast<const short8*>(xb + off);
            } else {
                u[2 * kb]     = *reinterpret_cast<const float4*>(xf + off);
                u[2 * kb + 1] = *reinterpret_cast<const float4*>(xf + off + 4);
            }
        }
        ns = nns; ne = nne;

        // ---------- Layer 1 (bias as C-init; per-kb convert) ----------
        f32x4 acc[4];
        ACC_INIT(acc, 0);
        #pragma unroll
        for (int kb = 0; kb < 4; ++kb) {
            short8 af;
            if constexpr (PREBF) {
                af = xa[kb];
            } else {
                uint4 tp_;
                tp_.x = pkbf(u[2 * kb].x,     u[2 * kb].y);
                tp_.y = pkbf(u[2 * kb].z,     u[2 * kb].w);
                tp_.z = pkbf(u[2 * kb + 1].x, u[2 * kb + 1].y);
                tp_.w = pkbf(u[2 * kb + 1].z, u[2 * kb + 1].w);
                af = __builtin_bit_cast(short8, tp_);
            }
            #pragma unroll
            for (int m = 0; m < 4; ++m) {
                const short8 wf = *reinterpret_cast<const short8*>(
                    &wlds[(m * 4 + kb) * 512 + lane * 8]);
                acc[m] = __builtin_amdgcn_mfma_f32_16x16x32_bf16(wf, af, acc[m], 0, 0, 0);
            }
        }
        LN_T(1, 2, acc);
        H_STORE(acc);

        // ---------- Layer 2 ----------
        f32x4 acc2[4];
        ACC_INIT(acc2, 3);
        L23_MFMA(acc2, 16);
        LN_T(4, 5, acc2);
        H_STORE(acc2);

        // ---------- Layer 3 ----------
        f32x4 acc3[4];
        ACC_INIT(acc3, 6);
        L23_MFMA(acc3, 24);
        LN_T(7, 8, acc3);

        // ---------- Layer 4 ----------
        float p = 0.f;
        #pragma unroll
        for (int m = 0; m < 4; ++m) {
            const float4 w4 = *reinterpret_cast<const float4*>(
                plds + 9 * 64 + m * 16 + kg4);
            p = fmaf(acc3[m][0], w4.x, p); p = fmaf(acc3[m][1], w4.y, p);
            p = fmaf(acc3[m][2], w4.z, p); p = fmaf(acc3[m][3], w4.w, p);
        }
        p += __shfl_xor(p, 16); p += __shfl_xor(p, 32);
        if (kg == 0) {
            const int e = (t << 4) + cl;
            if (e < E) {
                out[e] = __builtin_amdgcn_rcpf(
                    1.0f + __builtin_amdgcn_exp2f(p + b4s));
            }
        }
    }
}

__global__ __launch_bounds__(256) void cvt_x_bf16(const float* __restrict__ x,
                                                  unsigned short* __restrict__ xbf,
                                                  int n) {
    const int i = (blockIdx.x * 256 + threadIdx.x) * 8;
    if (i >= n) return;
    const float4 u0 = *reinterpret_cast<const float4*>(x + i);
    const float4 u1 = *reinterpret_cast<const float4*>(x + i + 4);
    uint4 t;
    t.x = pkbf(u0.x, u0.y); t.y = pkbf(u0.z, u0.w);
    t.z = pkbf(u1.x, u1.y); t.w = pkbf(u1.z, u1.w);
    *reinterpret_cast<uint4*>(xbf + i) = t;
}

extern "C" void kernel_launch(void* const* d_in, const int* in_sizes, int n_in,
                              void* d_out, int out_size, void* d_ws, size_t ws_size,
                              hipStream_t stream) {
    const float* x   = (const float*)d_in[0];
    const int*   ei  = (const int*)  d_in[1];
    const float* W1  = (const float*)d_in[2];
    const float* b1  = (const float*)d_in[3];
    const float* g1  = (const float*)d_in[4];
    const float* bt1 = (const float*)d_in[5];
    const float* W2  = (const float*)d_in[6];
    const float* b2  = (const float*)d_in[7];
    const float* g2  = (const float*)d_in[8];
    const float* bt2 = (const float*)d_in[9];
    const float* W3  = (const float*)d_in[10];
    const float* b3  = (const float*)d_in[11];
    const float* g3  = (const float*)d_in[12];
    const float* bt3 = (const float*)d_in[13];
    const float* W4  = (const float*)d_in[14];
    const float* b4  = (const float*)d_in[15];
    float* out = (float*)d_out;

    const int E  = in_sizes[1] / 2;
    const int nX = in_sizes[0];

    const bool prebf = (ws_size >= (size_t)nX * 2);

    if (prebf) {
        unsigned short* xbf = (unsigned short*)d_ws;
        const int grid_c = (nX / 8 + 255) / 256;
        hipLaunchKernelGGL(cvt_x_bf16, dim3(grid_c), dim3(256), 0, stream, x, xbf, nX);
        hipLaunchKernelGGL((edge_mlp_t<true>), dim3(GRID), dim3(BLOCK), 0, stream,
                           (const void*)xbf, ei, W1, b1, g1, bt1, W2, b2, g2, bt2,
                           W3, b3, g3, bt3, W4, b4, out, E);
    } else {
        hipLaunchKernelGGL((edge_mlp_t<false>), dim3(GRID), dim3(BLOCK), 0, stream,
                           (const void*)x, ei, W1, b1, g1, bt1, W2, b2, g2, bt2,
                           W3, b3, g3, bt3, W4, b4, out, E);
    }
}

// Round 17
// 138.171 us; speedup vs baseline: 1.8489x; 1.8489x over previous
//
#include <hip/hip_runtime.h>

#define BLOCK 512   // 8 waves
#define GRID  768   // 3 blocks/CU x 256 CU iff VGPR<=80; LDS 53760*3 <= 163840

typedef __attribute__((ext_vector_type(8))) short short8;   // 8 x bf16
typedef __attribute__((ext_vector_type(4))) float f32x4;    // MFMA C/D frag

#define TWOLOG2E  2.8853900817779268f
#define NLOG2E   -1.4426950408889634f
#define HP 72   // 144B pitch: 16B-aligned (R12); b128 reads 2-way = free

__device__ __forceinline__ unsigned short f2bf(float f) {
    unsigned u = __builtin_bit_cast(unsigned, f);
    u += 0x7FFFu + ((u >> 16) & 1u);
    return (unsigned short)(u >> 16);
}

__device__ __forceinline__ unsigned pkbf(float lo, float hi) {
    unsigned r;
    asm("v_cvt_pk_bf16_f32 %0, %1, %2" : "=v"(r) : "v"(lo), "v"(hi));
    return r;
}

__device__ __forceinline__ float tanh_z(float z) {
    float e = __builtin_amdgcn_exp2f(z);
    return fmaf(-2.0f, __builtin_amdgcn_rcpf(1.0f + e), 1.0f);
}

// LN+tanh; bias already in acc via MFMA C-init (stats-only prologue)
#define LN_T(PG, PT, A)                                                       \
    {                                                                         \
        float s_ = 0.f, q_ = 0.f;                                             \
        _Pragma("unroll")                                                     \
        for (int m = 0; m < 4; ++m) {                                         \
            s_ += (A[m][0] + A[m][1]) + (A[m][2] + A[m][3]);                  \
            q_ = fmaf(A[m][0], A[m][0], q_); q_ = fmaf(A[m][1], A[m][1], q_); \
            q_ = fmaf(A[m][2], A[m][2], q_); q_ = fmaf(A[m][3], A[m][3], q_); \
        }                                                                     \
        s_ += __shfl_xor(s_, 16); s_ += __shfl_xor(s_, 32);                   \
        q_ += __shfl_xor(q_, 16); q_ += __shfl_xor(q_, 32);                   \
        const float mu = s_ * 0.015625f;                                      \
        float var = fmaf(q_, 0.015625f, -mu * mu);                            \
        var = fmaxf(var, 0.0f);                                               \
        const float rs = __builtin_amdgcn_rsqf(var + 1e-5f);                  \
        const float mrs = mu * rs;                                            \
        _Pragma("unroll")                                                     \
        for (int m = 0; m < 4; ++m) {                                         \
            const float4 pg = *reinterpret_cast<const float4*>(               \
                plds + (PG) * 64 + m * 16 + kg4);                             \
            const float4 pt = *reinterpret_cast<const float4*>(               \
                plds + (PT) * 64 + m * 16 + kg4);                             \
            A[m][0] = tanh_z(fmaf(fmaf(A[m][0], rs, -mrs), pg.x, pt.x));      \
            A[m][1] = tanh_z(fmaf(fmaf(A[m][1], rs, -mrs), pg.y, pt.y));      \
            A[m][2] = tanh_z(fmaf(fmaf(A[m][2], rs, -mrs), pg.z, pt.z));      \
            A[m][3] = tanh_z(fmaf(fmaf(A[m][3], rs, -mrs), pg.w, pt.w));      \
        }                                                                     \
    }

#define H_STORE(A)                                                            \
    _Pragma("unroll")                                                         \
    for (int m = 0; m < 4; ++m) {                                             \
        uint2 u2;                                                             \
        u2.x = pkbf(A[m][0], A[m][1]);                                        \
        u2.y = pkbf(A[m][2], A[m][3]);                                        \
        *reinterpret_cast<uint2*>(hwv + cl * HP + m * 16 + kg4) = u2;         \
    }

#define ACC_INIT(ACC, PB)                                                     \
    _Pragma("unroll")                                                         \
    for (int m = 0; m < 4; ++m)                                               \
        ACC[m] = __builtin_bit_cast(f32x4, *reinterpret_cast<const float4*>(  \
            plds + (PB) * 64 + m * 16 + kg4));

#define L1_KB(AF, ACC, KB)                                                    \
    _Pragma("unroll")                                                         \
    for (int m = 0; m < 4; ++m) {                                             \
        const short8 wf = *reinterpret_cast<const short8*>(                   \
            &wlds[(m * 4 + (KB)) * 512 + lane * 8]);                          \
        ACC[m] = __builtin_amdgcn_mfma_f32_16x16x32_bf16(wf, AF, ACC[m], 0, 0, 0); \
    }

#define L23_MFMA(ACC, BASE)                                                   \
    _Pragma("unroll")                                                         \
    for (int kb = 0; kb < 2; ++kb) {                                          \
        const short8 hf = *reinterpret_cast<const short8*>(                   \
            hwv + cl * HP + kb * 32 + kg * 8);                                \
        _Pragma("unroll")                                                     \
        for (int m = 0; m < 4; ++m) {                                         \
            const short8 wf = *reinterpret_cast<const short8*>(               \
                &wlds[((BASE) + m * 2 + kb) * 512 + lane * 8]);               \
            ACC[m] = __builtin_amdgcn_mfma_f32_16x16x32_bf16(wf, hf, ACC[m], 0, 0, 0); \
        }                                                                     \
    }

#define LDIDX(T, A_, B_)                                                      \
    {                                                                         \
        const int tc_ = min((T), ntiles - 1);                                 \
        const int er_ = min((tc_ << 4) + cl, E - 1);                          \
        A_ = ei[er_]; B_ = ei[E + er_];                                       \
    }

template<bool PREBF>
__global__ __launch_bounds__(BLOCK) void edge_mlp_t(
    const void* __restrict__ xsrc, const int* __restrict__ ei,
    const float* __restrict__ W1, const float* __restrict__ b1,
    const float* __restrict__ g1, const float* __restrict__ bt1,
    const float* __restrict__ W2, const float* __restrict__ b2,
    const float* __restrict__ g2, const float* __restrict__ bt2,
    const float* __restrict__ W3, const float* __restrict__ b3,
    const float* __restrict__ g3, const float* __restrict__ bt3,
    const float* __restrict__ W4, const float* __restrict__ b4,
    float* __restrict__ out, int E)
{
    __shared__ unsigned short wlds[32 * 512];        // 32 KiB W^T frags
    __shared__ unsigned short hlds[8 * 16 * HP];     // 18 KiB per-wave h tiles
    __shared__ float plds[10 * 64];                  // 2.5 KiB params

    const int tid  = threadIdx.x;
    const int widx = tid >> 6;
    const int lane = tid & 63;
    const int kg   = lane >> 4;
    const int cl   = lane & 15;
    const int kg4  = kg * 4;

    for (int fi = widx; fi < 32; fi += 8) {
        const float* Wsrc; int m, kb;
        if (fi < 16) { Wsrc = W1; m = fi >> 2; kb = fi & 3; }
        else { int f = fi - 16; Wsrc = (f < 8) ? W2 : W3; f &= 7; m = f >> 1; kb = f & 1; }
        const float* src = Wsrc + (kb * 32 + kg * 8) * 64 + m * 16 + cl;
        short8 pk8;
        #pragma unroll
        for (int j = 0; j < 8; ++j) pk8[j] = (short)f2bf(src[j * 64]);
        *reinterpret_cast<short8*>(&wlds[fi * 512 + lane * 8]) = pk8;
    }
    for (int i = tid; i < 640; i += BLOCK) {
        const int p = i >> 6, c = i & 63;
        const float* sp; float sc;
        switch (p) {
            case 0: sp = b1;  sc = 1.0f;     break;
            case 1: sp = g1;  sc = TWOLOG2E; break;
            case 2: sp = bt1; sc = TWOLOG2E; break;
            case 3: sp = b2;  sc = 1.0f;     break;
            case 4: sp = g2;  sc = TWOLOG2E; break;
            case 5: sp = bt2; sc = TWOLOG2E; break;
            case 6: sp = b3;  sc = 1.0f;     break;
            case 7: sp = g3;  sc = TWOLOG2E; break;
            case 8: sp = bt3; sc = TWOLOG2E; break;
            default: sp = W4; sc = NLOG2E;   break;
        }
        plds[i] = sp[c] * sc;
    }
    const float b4s = b4[0] * NLOG2E;
    __syncthreads();

    const unsigned short* xb = (const unsigned short*)xsrc;
    const float*          xf = (const float*)xsrc;
    unsigned short* hwv = hlds + widx * (16 * HP);

    const int ntiles = (E + 15) >> 4;
    const int NW = (int)gridDim.x * 8;

    int t = (int)blockIdx.x * 8 + widx;
    int ns, ne;
    LDIDX(t, ns, ne);

    for (; t < ntiles; t += NW) {
        int nns, nne;
        LDIDX(t + NW, nns, nne);

        f32x4 acc[4];
        ACC_INIT(acc, 0);

        if constexpr (PREBF) {
            short8 xa[4];
            #pragma unroll
            for (int kb = 0; kb < 4; ++kb) {
                const unsigned off = (unsigned)(kb < 2 ? ns : ne) * 64u
                                   + (unsigned)((kb & 1) * 32 + kg * 8);
                xa[kb] = *reinterpret_cast<const short8*>(xb + off);
            }
            #pragma unroll
            for (int kb = 0; kb < 4; ++kb) { L1_KB(xa[kb], acc, kb); }
        } else {
            // staged gather: src + dst loads in flight together, but src f32
            // regs die early (convert+MFMA while dst still flying) -> lower peak
            const float* ps = xf + (unsigned)ns * 64u + kg * 8;
            const float* pd = xf + (unsigned)ne * 64u + kg * 8;
            const float4 s0 = *reinterpret_cast<const float4*>(ps);
            const float4 s1 = *reinterpret_cast<const float4*>(ps + 4);
            const float4 s2 = *reinterpret_cast<const float4*>(ps + 32);
            const float4 s3 = *reinterpret_cast<const float4*>(ps + 36);
            const float4 d0 = *reinterpret_cast<const float4*>(pd);
            const float4 d1 = *reinterpret_cast<const float4*>(pd + 4);
            const float4 d2 = *reinterpret_cast<const float4*>(pd + 32);
            const float4 d3 = *reinterpret_cast<const float4*>(pd + 36);
            {
                uint4 tp_;
                tp_.x = pkbf(s0.x, s0.y); tp_.y = pkbf(s0.z, s0.w);
                tp_.z = pkbf(s1.x, s1.y); tp_.w = pkbf(s1.z, s1.w);
                const short8 af0 = __builtin_bit_cast(short8, tp_);
                L1_KB(af0, acc, 0);
            }
            {
                uint4 tp_;
                tp_.x = pkbf(s2.x, s2.y); tp_.y = pkbf(s2.z, s2.w);
                tp_.z = pkbf(s3.x, s3.y); tp_.w = pkbf(s3.z, s3.w);
                const short8 af1 = __builtin_bit_cast(short8, tp_);
                L1_KB(af1, acc, 1);
            }
            {
                uint4 tp_;
                tp_.x = pkbf(d0.x, d0.y); tp_.y = pkbf(d0.z, d0.w);
                tp_.z = pkbf(d1.x, d1.y); tp_.w = pkbf(d1.z, d1.w);
                const short8 af2 = __builtin_bit_cast(short8, tp_);
                L1_KB(af2, acc, 2);
            }
            {
                uint4 tp_;
                tp_.x = pkbf(d2.x, d2.y); tp_.y = pkbf(d2.z, d2.w);
                tp_.z = pkbf(d3.x, d3.y); tp_.w = pkbf(d3.z, d3.w);
                const short8 af3 = __builtin_bit_cast(short8, tp_);
                L1_KB(af3, acc, 3);
            }
        }
        ns = nns; ne = nne;

        LN_T(1, 2, acc);
        H_STORE(acc);

        // ---------- Layer 2 ----------
        f32x4 acc2[4];
        ACC_INIT(acc2, 3);
        L23_MFMA(acc2, 16);
        LN_T(4, 5, acc2);
        H_STORE(acc2);

        // ---------- Layer 3 ----------
        f32x4 acc3[4];
        ACC_INIT(acc3, 6);
        L23_MFMA(acc3, 24);
        LN_T(7, 8, acc3);

        // ---------- Layer 4 ----------
        float p = 0.f;
        #pragma unroll
        for (int m = 0; m < 4; ++m) {
            const float4 w4 = *reinterpret_cast<const float4*>(
                plds + 9 * 64 + m * 16 + kg4);
            p = fmaf(acc3[m][0], w4.x, p); p = fmaf(acc3[m][1], w4.y, p);
            p = fmaf(acc3[m][2], w4.z, p); p = fmaf(acc3[m][3], w4.w, p);
        }
        p += __shfl_xor(p, 16); p += __shfl_xor(p, 32);
        if (kg == 0) {
            const int e = (t << 4) + cl;
            if (e < E) {
                out[e] = __builtin_amdgcn_rcpf(
                    1.0f + __builtin_amdgcn_exp2f(p + b4s));
            }
        }
    }
}

__global__ __launch_bounds__(256) void cvt_x_bf16(const float* __restrict__ x,
                                                  unsigned short* __restrict__ xbf,
                                                  int n) {
    const int i = (blockIdx.x * 256 + threadIdx.x) * 8;
    if (i >= n) return;
    const float4 u0 = *reinterpret_cast<const float4*>(x + i);
    const float4 u1 = *reinterpret_cast<const float4*>(x + i + 4);
    uint4 t;
    t.x = pkbf(u0.x, u0.y); t.y = pkbf(u0.z, u0.w);
    t.z = pkbf(u1.x, u1.y); t.w = pkbf(u1.z, u1.w);
    *reinterpret_cast<uint4*>(xbf + i) = t;
}

extern "C" void kernel_launch(void* const* d_in, const int* in_sizes, int n_in,
                              void* d_out, int out_size, void* d_ws, size_t ws_size,
                              hipStream_t stream) {
    const float* x   = (const float*)d_in[0];
    const int*   ei  = (const int*)  d_in[1];
    const float* W1  = (const float*)d_in[2];
    const float* b1  = (const float*)d_in[3];
    const float* g1  = (const float*)d_in[4];
    const float* bt1 = (const float*)d_in[5];
    const float* W2  = (const float*)d_in[6];
    const float* b2  = (const float*)d_in[7];
    const float* g2  = (const float*)d_in[8];
    const float* bt2 = (const float*)d_in[9];
    const float* W3  = (const float*)d_in[10];
    const float* b3  = (const float*)d_in[11];
    const float* g3  = (const float*)d_in[12];
    const float* bt3 = (const float*)d_in[13];
    const float* W4  = (const float*)d_in[14];
    const float* b4  = (const float*)d_in[15];
    float* out = (float*)d_out;

    const int E  = in_sizes[1] / 2;
    const int nX = in_sizes[0];

    const bool prebf = (ws_size >= (size_t)nX * 2);

    if (prebf) {
        unsigned short* xbf = (unsigned short*)d_ws;
        const int grid_c = (nX / 8 + 255) / 256;
        hipLaunchKernelGGL(cvt_x_bf16, dim3(grid_c), dim3(256), 0, stream, x, xbf, nX);
        hipLaunchKernelGGL((edge_mlp_t<true>), dim3(GRID), dim3(BLOCK), 0, stream,
                           (const void*)xbf, ei, W1, b1, g1, bt1, W2, b2, g2, bt2,
                           W3, b3, g3, bt3, W4, b4, out, E);
    } else {
        hipLaunchKernelGGL((edge_mlp_t<false>), dim3(GRID), dim3(BLOCK), 0, stream,
                           (const void*)x, ei, W1, b1, g1, bt1, W2, b2, g2, bt2,
                           W3, b3, g3, bt3, W4, b4, out, E);
    }
}

// Round 18
// 94.411 us; speedup vs baseline: 2.7059x; 1.4635x over previous
//
#include <hip/hip_runtime.h>

#define BLOCK 512   // 8 waves
#define GRID  512   // 2 blocks/CU resident (4 waves/SIMD VGPR tier = hard ceiling)

typedef __attribute__((ext_vector_type(8))) short short8;   // 8 x bf16
typedef __attribute__((ext_vector_type(4))) float f32x4;    // MFMA C/D frag

#define TWOLOG2E  2.8853900817779268f
#define NLOG2E   -1.4426950408889634f
#define HP 72   // 144B pitch: 16B-aligned (R12); b128 reads 2-way = free

__device__ __forceinline__ unsigned short f2bf(float f) {
    unsigned u = __builtin_bit_cast(unsigned, f);
    u += 0x7FFFu + ((u >> 16) & 1u);
    return (unsigned short)(u >> 16);
}

__device__ __forceinline__ unsigned pkbf(float lo, float hi) {
    unsigned r;
    asm("v_cvt_pk_bf16_f32 %0, %1, %2" : "=v"(r) : "v"(lo), "v"(hi));
    return r;
}

__device__ __forceinline__ float tanh_z(float z) {
    float e = __builtin_amdgcn_exp2f(z);
    return fmaf(-2.0f, __builtin_amdgcn_rcpf(1.0f + e), 1.0f);
}

// ---- dual-tile LN+tanh: stats per tile, ONE shared pg/pt LDS read pair ----
#define LN_DUAL(PG, PT, A, B)                                                 \
    {                                                                         \
        float sA = 0.f, qA = 0.f, sB = 0.f, qB = 0.f;                         \
        _Pragma("unroll")                                                     \
        for (int m = 0; m < 4; ++m) {                                         \
            sA += (A[m][0] + A[m][1]) + (A[m][2] + A[m][3]);                  \
            qA = fmaf(A[m][0], A[m][0], qA); qA = fmaf(A[m][1], A[m][1], qA); \
            qA = fmaf(A[m][2], A[m][2], qA); qA = fmaf(A[m][3], A[m][3], qA); \
            sB += (B[m][0] + B[m][1]) + (B[m][2] + B[m][3]);                  \
            qB = fmaf(B[m][0], B[m][0], qB); qB = fmaf(B[m][1], B[m][1], qB); \
            qB = fmaf(B[m][2], B[m][2], qB); qB = fmaf(B[m][3], B[m][3], qB); \
        }                                                                     \
        sA += __shfl_xor(sA, 16); sB += __shfl_xor(sB, 16);                   \
        qA += __shfl_xor(qA, 16); qB += __shfl_xor(qB, 16);                   \
        sA += __shfl_xor(sA, 32); sB += __shfl_xor(sB, 32);                   \
        qA += __shfl_xor(qA, 32); qB += __shfl_xor(qB, 32);                   \
        const float muA = sA * 0.015625f, muB = sB * 0.015625f;               \
        float vA = fmaf(qA, 0.015625f, -muA * muA);                           \
        float vB = fmaf(qB, 0.015625f, -muB * muB);                           \
        vA = fmaxf(vA, 0.0f); vB = fmaxf(vB, 0.0f);                           \
        const float rsA = __builtin_amdgcn_rsqf(vA + 1e-5f);                  \
        const float rsB = __builtin_amdgcn_rsqf(vB + 1e-5f);                  \
        const float mrsA = muA * rsA, mrsB = muB * rsB;                       \
        _Pragma("unroll")                                                     \
        for (int m = 0; m < 4; ++m) {                                         \
            const float4 pg = *reinterpret_cast<const float4*>(               \
                plds + (PG) * 64 + m * 16 + kg4);                             \
            const float4 pt = *reinterpret_cast<const float4*>(               \
                plds + (PT) * 64 + m * 16 + kg4);                             \
            A[m][0] = tanh_z(fmaf(fmaf(A[m][0], rsA, -mrsA), pg.x, pt.x));    \
            A[m][1] = tanh_z(fmaf(fmaf(A[m][1], rsA, -mrsA), pg.y, pt.y));    \
            A[m][2] = tanh_z(fmaf(fmaf(A[m][2], rsA, -mrsA), pg.z, pt.z));    \
            A[m][3] = tanh_z(fmaf(fmaf(A[m][3], rsA, -mrsA), pg.w, pt.w));    \
            B[m][0] = tanh_z(fmaf(fmaf(B[m][0], rsB, -mrsB), pg.x, pt.x));    \
            B[m][1] = tanh_z(fmaf(fmaf(B[m][1], rsB, -mrsB), pg.y, pt.y));    \
            B[m][2] = tanh_z(fmaf(fmaf(B[m][2], rsB, -mrsB), pg.z, pt.z));    \
            B[m][3] = tanh_z(fmaf(fmaf(B[m][3], rsB, -mrsB), pg.w, pt.w));    \
        }                                                                     \
    }

#define H_STORE(A, HW)                                                        \
    _Pragma("unroll")                                                         \
    for (int m = 0; m < 4; ++m) {                                             \
        uint2 u2;                                                             \
        u2.x = pkbf(A[m][0], A[m][1]);                                        \
        u2.y = pkbf(A[m][2], A[m][3]);                                        \
        *reinterpret_cast<uint2*>((HW) + cl * HP + m * 16 + kg4) = u2;        \
    }

// bias as MFMA C-init: ONE pb read seeds both tiles' accumulators
#define ACC_INIT_DUAL(ACCA, ACCB, PB)                                         \
    _Pragma("unroll")                                                         \
    for (int m = 0; m < 4; ++m) {                                             \
        const f32x4 pb = __builtin_bit_cast(f32x4,                            \
            *reinterpret_cast<const float4*>(plds + (PB) * 64 + m * 16 + kg4)); \
        ACCA[m] = pb; ACCB[m] = pb;                                           \
    }

// Layer 1 dual: each wf read feeds BOTH tiles; setprio(1) keeps the MFMA
// pipe favored while other (barrier-free, phase-independent) waves do VALU
#define L1_DUAL(AFA, AFB, ACCA, ACCB)                                         \
    __builtin_amdgcn_s_setprio(1);                                            \
    _Pragma("unroll")                                                         \
    for (int kb = 0; kb < 4; ++kb) {                                          \
        _Pragma("unroll")                                                     \
        for (int m = 0; m < 4; ++m) {                                         \
            const short8 wf = *reinterpret_cast<const short8*>(               \
                &wlds[(m * 4 + kb) * 512 + lane * 8]);                        \
            ACCA[m] = __builtin_amdgcn_mfma_f32_16x16x32_bf16(wf, AFA[kb], ACCA[m], 0, 0, 0); \
            ACCB[m] = __builtin_amdgcn_mfma_f32_16x16x32_bf16(wf, AFB[kb], ACCB[m], 0, 0, 0); \
        }                                                                     \
    }                                                                         \
    __builtin_amdgcn_s_setprio(0);

#define L23_DUAL(ACCA, ACCB, BASE)                                            \
    __builtin_amdgcn_s_setprio(1);                                            \
    _Pragma("unroll")                                                         \
    for (int kb = 0; kb < 2; ++kb) {                                          \
        const short8 hfA = *reinterpret_cast<const short8*>(                  \
            hwvA + cl * HP + kb * 32 + kg * 8);                               \
        const short8 hfB = *reinterpret_cast<const short8*>(                  \
            hwvB + cl * HP + kb * 32 + kg * 8);                               \
        _Pragma("unroll")                                                     \
        for (int m = 0; m < 4; ++m) {                                         \
            const short8 wf = *reinterpret_cast<const short8*>(               \
                &wlds[((BASE) + m * 2 + kb) * 512 + lane * 8]);               \
            ACCA[m] = __builtin_amdgcn_mfma_f32_16x16x32_bf16(wf, hfA, ACCA[m], 0, 0, 0); \
            ACCB[m] = __builtin_amdgcn_mfma_f32_16x16x32_bf16(wf, hfB, ACCB[m], 0, 0, 0); \
        }                                                                     \
    }                                                                         \
    __builtin_amdgcn_s_setprio(0);

#define GATHER_F(U, NS, NE)                                                   \
    _Pragma("unroll")                                                         \
    for (int kb = 0; kb < 4; ++kb) {                                          \
        const unsigned off = (unsigned)(kb < 2 ? (NS) : (NE)) * 64u           \
                           + (unsigned)((kb & 1) * 32 + kg * 8);              \
        U[2 * kb]     = *reinterpret_cast<const float4*>(xf + off);           \
        U[2 * kb + 1] = *reinterpret_cast<const float4*>(xf + off + 4);       \
    }

#define GATHER_B(XA, NS, NE)                                                  \
    _Pragma("unroll")                                                         \
    for (int kb = 0; kb < 4; ++kb) {                                          \
        const unsigned off = (unsigned)(kb < 2 ? (NS) : (NE)) * 64u           \
                           + (unsigned)((kb & 1) * 32 + kg * 8);              \
        XA[kb] = *reinterpret_cast<const short8*>(xb + off);                  \
    }

#define CVT8(U, AF)                                                           \
    _Pragma("unroll")                                                         \
    for (int kb = 0; kb < 4; ++kb) {                                          \
        uint4 tp_;                                                            \
        tp_.x = pkbf(U[2 * kb].x,     U[2 * kb].y);                           \
        tp_.y = pkbf(U[2 * kb].z,     U[2 * kb].w);                           \
        tp_.z = pkbf(U[2 * kb + 1].x, U[2 * kb + 1].y);                       \
        tp_.w = pkbf(U[2 * kb + 1].z, U[2 * kb + 1].w);                       \
        AF[kb] = __builtin_bit_cast(short8, tp_);                             \
    }

#define LDIDX(T, A_, B_)                                                      \
    {                                                                         \
        const int tc_ = min((T), ntiles - 1);                                 \
        const int er_ = min((tc_ << 4) + cl, E - 1);                          \
        A_ = ei[er_]; B_ = ei[E + er_];                                       \
    }

template<bool PREBF>
__global__ __launch_bounds__(BLOCK) void edge_mlp_t(
    const void* __restrict__ xsrc, const int* __restrict__ ei,
    const float* __restrict__ W1, const float* __restrict__ b1,
    const float* __restrict__ g1, const float* __restrict__ bt1,
    const float* __restrict__ W2, const float* __restrict__ b2,
    const float* __restrict__ g2, const float* __restrict__ bt2,
    const float* __restrict__ W3, const float* __restrict__ b3,
    const float* __restrict__ g3, const float* __restrict__ bt3,
    const float* __restrict__ W4, const float* __restrict__ b4,
    float* __restrict__ out, int E)
{
    __shared__ unsigned short wlds[32 * 512];            // 32 KiB W^T frags
    __shared__ unsigned short hlds[8 * 2 * 16 * HP];     // 2 h-tiles per wave
    __shared__ float plds[10 * 64];

    const int tid  = threadIdx.x;
    const int widx = tid >> 6;
    const int lane = tid & 63;
    const int kg   = lane >> 4;
    const int cl   = lane & 15;
    const int kg4  = kg * 4;

    for (int fi = widx; fi < 32; fi += 8) {
        const float* Wsrc; int m, kb;
        if (fi < 16) { Wsrc = W1; m = fi >> 2; kb = fi & 3; }
        else { int f = fi - 16; Wsrc = (f < 8) ? W2 : W3; f &= 7; m = f >> 1; kb = f & 1; }
        const float* src = Wsrc + (kb * 32 + kg * 8) * 64 + m * 16 + cl;
        short8 pk8;
        #pragma unroll
        for (int j = 0; j < 8; ++j) pk8[j] = (short)f2bf(src[j * 64]);
        *reinterpret_cast<short8*>(&wlds[fi * 512 + lane * 8]) = pk8;
    }
    for (int i = tid; i < 640; i += BLOCK) {
        const int p = i >> 6, c = i & 63;
        const float* sp; float sc;
        switch (p) {
            case 0: sp = b1;  sc = 1.0f;     break;
            case 1: sp = g1;  sc = TWOLOG2E; break;
            case 2: sp = bt1; sc = TWOLOG2E; break;
            case 3: sp = b2;  sc = 1.0f;     break;
            case 4: sp = g2;  sc = TWOLOG2E; break;
            case 5: sp = bt2; sc = TWOLOG2E; break;
            case 6: sp = b3;  sc = 1.0f;     break;
            case 7: sp = g3;  sc = TWOLOG2E; break;
            case 8: sp = bt3; sc = TWOLOG2E; break;
            default: sp = W4; sc = NLOG2E;   break;
        }
        plds[i] = sp[c] * sc;
    }
    const float b4s = b4[0] * NLOG2E;
    __syncthreads();

    const unsigned short* xb = (const unsigned short*)xsrc;
    const float*          xf = (const float*)xsrc;
    unsigned short* hwvA = hlds + widx * (2 * 16 * HP);
    unsigned short* hwvB = hwvA + 16 * HP;

    const int ntiles = (E + 15) >> 4;
    const int NW = (int)gridDim.x * 8;

    int t = (int)blockIdx.x * 8 + widx;
    int nsA, neA, nsB, neB;
    LDIDX(t, nsA, neA);
    LDIDX(t + NW, nsB, neB);

    for (; t < ntiles; t += 2 * NW) {
        const int tb = t + NW;

        float4 uA[8], uB[8];
        short8 afA[4], afB[4];
        if constexpr (PREBF) {
            GATHER_B(afA, nsA, neA);
            GATHER_B(afB, nsB, neB);
        } else {
            GATHER_F(uA, nsA, neA);
            GATHER_F(uB, nsB, neB);
        }
        LDIDX(t + 2 * NW, nsA, neA);
        LDIDX(t + 3 * NW, nsB, neB);
        if constexpr (!PREBF) {
            CVT8(uA, afA);
            CVT8(uB, afB);
        }

        // ---------- Layer 1 (shared wf + shared bias C-init) ----------
        f32x4 accA[4], accB[4];
        ACC_INIT_DUAL(accA, accB, 0);
        L1_DUAL(afA, afB, accA, accB);
        LN_DUAL(1, 2, accA, accB);
        H_STORE(accA, hwvA);
        H_STORE(accB, hwvB);

        // ---------- Layer 2 ----------
        f32x4 acc2A[4], acc2B[4];
        ACC_INIT_DUAL(acc2A, acc2B, 3);
        L23_DUAL(acc2A, acc2B, 16);
        LN_DUAL(4, 5, acc2A, acc2B);
        H_STORE(acc2A, hwvA);
        H_STORE(acc2B, hwvB);

        // ---------- Layer 3 ----------
        f32x4 acc3A[4], acc3B[4];
        ACC_INIT_DUAL(acc3A, acc3B, 6);
        L23_DUAL(acc3A, acc3B, 24);
        LN_DUAL(7, 8, acc3A, acc3B);

        // ---------- Layer 4: shared w4 reads ----------
        float pA = 0.f, pB = 0.f;
        #pragma unroll
        for (int m = 0; m < 4; ++m) {
            const float4 w4 = *reinterpret_cast<const float4*>(
                plds + 9 * 64 + m * 16 + kg4);
            pA = fmaf(acc3A[m][0], w4.x, pA); pA = fmaf(acc3A[m][1], w4.y, pA);
            pA = fmaf(acc3A[m][2], w4.z, pA); pA = fmaf(acc3A[m][3], w4.w, pA);
            pB = fmaf(acc3B[m][0], w4.x, pB); pB = fmaf(acc3B[m][1], w4.y, pB);
            pB = fmaf(acc3B[m][2], w4.z, pB); pB = fmaf(acc3B[m][3], w4.w, pB);
        }
        pA += __shfl_xor(pA, 16); pB += __shfl_xor(pB, 16);
        pA += __shfl_xor(pA, 32); pB += __shfl_xor(pB, 32);
        if (kg == 0) {
            const int eA = (t << 4) + cl;
            if (eA < E) out[eA] = __builtin_amdgcn_rcpf(
                1.0f + __builtin_amdgcn_exp2f(pA + b4s));
            const int eB = (tb << 4) + cl;
            if (eB < E) out[eB] = __builtin_amdgcn_rcpf(
                1.0f + __builtin_amdgcn_exp2f(pB + b4s));
        }
    }
}

__global__ __launch_bounds__(256) void cvt_x_bf16(const float* __restrict__ x,
                                                  unsigned short* __restrict__ xbf,
                                                  int n) {
    const int i = (blockIdx.x * 256 + threadIdx.x) * 8;
    if (i >= n) return;
    const float4 u0 = *reinterpret_cast<const float4*>(x + i);
    const float4 u1 = *reinterpret_cast<const float4*>(x + i + 4);
    uint4 t;
    t.x = pkbf(u0.x, u0.y); t.y = pkbf(u0.z, u0.w);
    t.z = pkbf(u1.x, u1.y); t.w = pkbf(u1.z, u1.w);
    *reinterpret_cast<uint4*>(xbf + i) = t;
}

extern "C" void kernel_launch(void* const* d_in, const int* in_sizes, int n_in,
                              void* d_out, int out_size, void* d_ws, size_t ws_size,
                              hipStream_t stream) {
    const float* x   = (const float*)d_in[0];
    const int*   ei  = (const int*)  d_in[1];
    const float* W1  = (const float*)d_in[2];
    const float* b1  = (const float*)d_in[3];
    const float* g1  = (const float*)d_in[4];
    const float* bt1 = (const float*)d_in[5];
    const float* W2  = (const float*)d_in[6];
    const float* b2  = (const float*)d_in[7];
    const float* g2  = (const float*)d_in[8];
    const float* bt2 = (const float*)d_in[9];
    const float* W3  = (const float*)d_in[10];
    const float* b3  = (const float*)d_in[11];
    const float* g3  = (const float*)d_in[12];
    const float* bt3 = (const float*)d_in[13];
    const float* W4  = (const float*)d_in[14];
    const float* b4  = (const float*)d_in[15];
    float* out = (float*)d_out;

    const int E  = in_sizes[1] / 2;
    const int nX = in_sizes[0];

    const bool prebf = (ws_size >= (size_t)nX * 2);

    if (prebf) {
        unsigned short* xbf = (unsigned short*)d_ws;
        const int grid_c = (nX / 8 + 255) / 256;
        hipLaunchKernelGGL(cvt_x_bf16, dim3(grid_c), dim3(256), 0, stream, x, xbf, nX);
        hipLaunchKernelGGL((edge_mlp_t<true>), dim3(GRID), dim3(BLOCK), 0, stream,
                           (const void*)xbf, ei, W1, b1, g1, bt1, W2, b2, g2, bt2,
                           W3, b3, g3, bt3, W4, b4, out, E);
    } else {
        hipLaunchKernelGGL((edge_mlp_t<false>), dim3(GRID), dim3(BLOCK), 0, stream,
                           (const void*)x, ei, W1, b1, g1, bt1, W2, b2, g2, bt2,
                           W3, b3, g3, bt3, W4, b4, out, E);
    }
}